// Round 1
// baseline (92.055 us; speedup 1.0000x reference)
//
#include <hip/hip_runtime.h>

// Problem geometry (fixed by reference setup_inputs()):
//   src: [B=4, N=8192, 3] f32
//   dst: [B=4, S=2048, 3] f32
//   out: [B, N, S] f32 = softmax_S( exp( -0.5 * ||src_n - dst_s|| ) )
#define BB 4
#define NN 8192
#define SS 2048

// One block per (b, n) row. 256 threads; each thread computes 8 s-values as
// two groups of 4 consecutive (float4-coalesced loads and stores).
__global__ __launch_bounds__(256)
void gauss_softmax_kernel(const float* __restrict__ src,
                          const float* __restrict__ dst,
                          float* __restrict__ out) {
    const int n   = blockIdx.x;
    const int b   = blockIdx.y;
    const int tid = threadIdx.x;

    // Broadcast src point for this row (scalar loads, L2-resident).
    const float sx = src[((size_t)(b * NN + n)) * 3 + 0];
    const float sy = src[((size_t)(b * NN + n)) * 3 + 1];
    const float sz = src[((size_t)(b * NN + n)) * 3 + 2];

    const float* dstb = dst + (size_t)b * SS * 3;

    float v[8];
    float local = 0.0f;

    #pragma unroll
    for (int k = 0; k < 2; ++k) {
        const int s0 = tid * 4 + k * 1024;           // 4 consecutive s-values
        // 4 points * 3 floats = 48 bytes, 16B-aligned (s0*3*4 = tid*48 + k*12288)
        const float4 p0 = *reinterpret_cast<const float4*>(dstb + (size_t)s0 * 3 + 0);
        const float4 p1 = *reinterpret_cast<const float4*>(dstb + (size_t)s0 * 3 + 4);
        const float4 p2 = *reinterpret_cast<const float4*>(dstb + (size_t)s0 * 3 + 8);
        // points: (p0.x p0.y p0.z) (p0.w p1.x p1.y) (p1.z p1.w p2.x) (p2.y p2.z p2.w)
        const float px[4] = {p0.x, p0.w, p1.z, p2.y};
        const float py[4] = {p0.y, p1.x, p1.w, p2.z};
        const float pz[4] = {p0.z, p1.y, p2.x, p2.w};
        #pragma unroll
        for (int j = 0; j < 4; ++j) {
            const float dx = sx - px[j];
            const float dy = sy - py[j];
            const float dz = sz - pz[j];
            const float d2 = fmaxf(dx * dx + dy * dy + dz * dz, 1e-12f);
            const float dist = sqrtf(d2);
            const float t = expf(expf(-0.5f * dist));  // softmax arg then exp
            v[k * 4 + j] = t;
            local += t;
        }
    }

    // Row sum: wave64 butterfly then cross-wave combine in LDS.
    #pragma unroll
    for (int off = 32; off >= 1; off >>= 1)
        local += __shfl_down(local, off, 64);

    __shared__ float wsum[4];
    const int lane = tid & 63;
    const int wid  = tid >> 6;
    if (lane == 0) wsum[wid] = local;
    __syncthreads();
    const float inv = 1.0f / (wsum[0] + wsum[1] + wsum[2] + wsum[3]);

    float* outp = out + ((size_t)(b * NN + n)) * SS;
    #pragma unroll
    for (int k = 0; k < 2; ++k) {
        const int s0 = tid * 4 + k * 1024;
        float4 o;
        o.x = v[k * 4 + 0] * inv;
        o.y = v[k * 4 + 1] * inv;
        o.z = v[k * 4 + 2] * inv;
        o.w = v[k * 4 + 3] * inv;
        *reinterpret_cast<float4*>(outp + s0) = o;
    }
}

extern "C" void kernel_launch(void* const* d_in, const int* in_sizes, int n_in,
                              void* d_out, int out_size, void* d_ws, size_t ws_size,
                              hipStream_t stream) {
    const float* src = (const float*)d_in[0];  // [4, 8192, 3]
    const float* dst = (const float*)d_in[1];  // [4, 2048, 3]
    float* out = (float*)d_out;                // [4, 8192, 2048]

    dim3 grid(NN, BB);
    dim3 block(256);
    gauss_softmax_kernel<<<grid, block, 0, stream>>>(src, dst, out);
}

// Round 2
// 48.475 us; speedup vs baseline: 1.8990x; 1.8990x over previous
//
#include <hip/hip_runtime.h>

// Problem geometry (fixed by reference setup_inputs()):
//   src: [B=4, N=8192, 3] f32
//   dst: [B=4, S=2048, 3] f32
//   out: [B, N, S] f32 = softmax_S( exp( -0.5 * ||src_n - dst_s|| ) )
#define BB 4
#define NN 8192
#define SS 2048
#define ROWS 4   // rows (n-values) per block; dst coords stay in registers

#define L2E  1.4426950408889634f   // log2(e)
#define NL2E 0.7213475204444817f   // 0.5 * log2(e)

// One block per ROWS consecutive (b, n) rows. 256 threads; each thread owns 8
// s-values (two groups of 4 consecutive -> float4 loads/stores), reused
// across ROWS rows.
__global__ __launch_bounds__(256)
void gauss_softmax_kernel(const float* __restrict__ src,
                          const float* __restrict__ dst,
                          float* __restrict__ out) {
    const int n0  = blockIdx.x * ROWS;
    const int b   = blockIdx.y;
    const int tid = threadIdx.x;

    const float* dstb = dst + (size_t)b * SS * 3;

    // Load this thread's 8 dst points once (registers), reuse across ROWS.
    float px[8], py[8], pz[8];
    #pragma unroll
    for (int k = 0; k < 2; ++k) {
        const int s0 = tid * 4 + k * 1024;  // 48B-aligned: tid*48 + k*12288
        const float4 p0 = *reinterpret_cast<const float4*>(dstb + (size_t)s0 * 3 + 0);
        const float4 p1 = *reinterpret_cast<const float4*>(dstb + (size_t)s0 * 3 + 4);
        const float4 p2 = *reinterpret_cast<const float4*>(dstb + (size_t)s0 * 3 + 8);
        px[k*4+0] = p0.x; py[k*4+0] = p0.y; pz[k*4+0] = p0.z;
        px[k*4+1] = p0.w; py[k*4+1] = p1.x; pz[k*4+1] = p1.y;
        px[k*4+2] = p1.z; py[k*4+2] = p1.w; pz[k*4+2] = p2.x;
        px[k*4+3] = p2.y; py[k*4+3] = p2.z; pz[k*4+3] = p2.w;
    }

    __shared__ float wsum[ROWS][4];
    const int lane = tid & 63;
    const int wid  = tid >> 6;

    float v[ROWS][8];

    #pragma unroll
    for (int r = 0; r < ROWS; ++r) {
        const size_t row = (size_t)(b * NN + n0 + r);
        const float sx = src[row * 3 + 0];
        const float sy = src[row * 3 + 1];
        const float sz = src[row * 3 + 2];

        float local = 0.0f;
        #pragma unroll
        for (int j = 0; j < 8; ++j) {
            const float dx = sx - px[j];
            const float dy = sy - py[j];
            const float dz = sz - pz[j];
            const float d2 = fmaxf(dx * dx + dy * dy + dz * dz, 1e-12f);
            const float dist = __builtin_amdgcn_sqrtf(d2);
            // exp(exp(-0.5*dist)) = exp2(L2E * exp2(-0.5*L2E*dist))
            const float inner = __builtin_amdgcn_exp2f(-NL2E * dist);
            const float t = __builtin_amdgcn_exp2f(L2E * inner);
            v[r][j] = t;
            local += t;
        }

        // wave64 butterfly reduce
        #pragma unroll
        for (int off = 32; off >= 1; off >>= 1)
            local += __shfl_down(local, off, 64);
        if (lane == 0) wsum[r][wid] = local;
    }

    __syncthreads();

    #pragma unroll
    for (int r = 0; r < ROWS; ++r) {
        const float inv = 1.0f / (wsum[r][0] + wsum[r][1] + wsum[r][2] + wsum[r][3]);
        float* outp = out + (size_t)(b * NN + n0 + r) * SS;
        #pragma unroll
        for (int k = 0; k < 2; ++k) {
            const int s0 = tid * 4 + k * 1024;
            float4 o;
            o.x = v[r][k*4+0] * inv;
            o.y = v[r][k*4+1] * inv;
            o.z = v[r][k*4+2] * inv;
            o.w = v[r][k*4+3] * inv;
            *reinterpret_cast<float4*>(outp + s0) = o;
        }
    }
}

extern "C" void kernel_launch(void* const* d_in, const int* in_sizes, int n_in,
                              void* d_out, int out_size, void* d_ws, size_t ws_size,
                              hipStream_t stream) {
    const float* src = (const float*)d_in[0];  // [4, 8192, 3]
    const float* dst = (const float*)d_in[1];  // [4, 2048, 3]
    float* out = (float*)d_out;                // [4, 8192, 2048]

    dim3 grid(NN / ROWS, BB);
    dim3 block(256);
    gauss_softmax_kernel<<<grid, block, 0, stream>>>(src, dst, out);
}